// Round 12
// baseline (1496.643 us; speedup 1.0000x reference)
//
#include <hip/hip_runtime.h>
#include <hip/hip_bf16.h>

// ---------------------------------------------------------------------------
// TTT meta-adapter fused step, round 12.
// rows = B*S = 4096, H = 1024, R = 16, V = 32000, N_valid = 4094.
// k_fused: phase-1 in FP8 (Bp1 + adapted e4m3, mfma fp8_fp8) -> lA+lP fit in
// 67 KB LDS -> TWO independent 512-thread blocks per CU (512 blocks total)
// so one block's phase-1 VMEM overlaps the other's phase-3 LDS/MFMA.
// Gradient path (P, Bp2, phase 3) stays bf16. m=0 softmax (proven R7+).
// ---------------------------------------------------------------------------

#define ROWS 4096
#define Hdim 1024
#define Rdim 16
#define Vdim 32000
#define NVALID 4094.0f
#define LRATE 0.01f
#define RB 32          // rows per block in fused kernel
#define VT 512         // V-tile
#define SPW 8000       // V-cols per split (4 splits)
#define LAS 1032       // lA row stride bytes (fp8): 2-bank offset/row, conflict-free
#define LPS 1040       // lP row stride bytes (bf16): 16B-aligned, 4-bank offset/row

typedef __attribute__((ext_vector_type(8))) short bf16x8;
typedef __attribute__((ext_vector_type(4))) float f32x4;

static __device__ __forceinline__ float bf2f(short u) {
  union { float f; unsigned int i; } w; w.i = ((unsigned int)(unsigned short)u) << 16; return w.f;
}
static __device__ __forceinline__ short f2bf(float f) {
  union { float f; unsigned int i; } w; w.f = f;
  unsigned int lsb = (w.i >> 16) & 1u;
  w.i += 0x7fffu + lsb;                 // round-to-nearest-even
  return (short)(w.i >> 16);
}
static __device__ __forceinline__ f32x4 mfma16(bf16x8 a, bf16x8 b, f32x4 c) {
  return __builtin_amdgcn_mfma_f32_16x16x32_bf16(a, b, c, 0, 0, 0);
}
static __device__ __forceinline__ f32x4 mfma8(long a, long b, f32x4 c) {
  return __builtin_amdgcn_mfma_f32_16x16x32_fp8_fp8(a, b, c, 0, 0, 0);
}
static __device__ __forceinline__ int pk4fp8(float f0, float f1, float f2, float f3) {
  int v = __builtin_amdgcn_cvt_pk_fp8_f32(f0, f1, 0, false);
  v = __builtin_amdgcn_cvt_pk_fp8_f32(f2, f3, v, true);
  return v;
}

// ---------------- workspace layout (bytes) ----------------
#define OFF_BP2   ((size_t)0)                    // lm_head bf16 packed [64][1000][512]   65,536,000
#define OFF_BP1   ((size_t)65536000)             // lmhT fp8 packed [2000][32][512B]      32,768,000
#define OFF_ADP   ((size_t)98304000)             // adapted bf16 [ROWS][H]                 8,388,608
#define OFF_ADP8  ((size_t)106692608)            // adapted fp8 [ROWS][H]                  4,194,304
#define OFF_DAX   ((size_t)110886912)            // dApart bf16 [ROWS][4][H]; f32 overlay 33,554,432
#define OFF_U     ((size_t)144441344)            // u f32                                    262,144
#define OFF_DU    ((size_t)144703488)            // du f32                                   262,144
#define OFF_Z     ((size_t)144965632)            // zpart f32 [4][ROWS]                       65,536
#define OFF_GA    ((size_t)145031168)            // ga f32                                    65,536
#define OFF_GB    ((size_t)145096704)            // gb f32                                    65,536
#define OFF_LOSS  ((size_t)145162240)            // loss accumulator                               4

// ---------------- output layout (floats) ----------------
#define OUT_A    ((size_t)4194304)
#define OUT_B    ((size_t)4210688)
#define OUT_LOSS ((size_t)4227072)
#define OUT_GN   ((size_t)4227073)

// ===================== pack lm_head: Bp1 fp8 (v-major), Bp2 bf16 (h-major) ==========
// Bp1[vb][kb][lane][8B]: elem (v,k)=lm_head[k][v], lane=(v&15)+16*((k>>3)&3), j=k&7
// Bp2[hb][vkb][lane][8]: elem (h,v)=lm_head[h][v], lane=(h&15)+16*((v>>3)&3), j=v&7
__global__ void k_pack(const float* __restrict__ in, char* __restrict__ Bp1,
                       short* __restrict__ Bp2) {
  __shared__ float tile[32][260];
  int v0 = blockIdx.x * 256, k0 = blockIdx.y * 32;
  int tid = threadIdx.x;
#pragma unroll
  for (int r = 0; r < 32; ++r)
    tile[r][tid] = in[(size_t)(k0 + r) * Vdim + v0 + tid];
  __syncthreads();
  int lane = tid & 63, l15 = lane & 15, q = (lane >> 4) & 3, g = tid >> 6;
#pragma unroll
  for (int it = 0; it < 4; ++it) {
    int vbl = it * 4 + g;                 // 0..15
    float f[8];
#pragma unroll
    for (int j = 0; j < 8; ++j) f[j] = tile[q * 8 + j][vbl * 16 + l15];
    int2 w2;
    w2.x = pk4fp8(f[0], f[1], f[2], f[3]);
    w2.y = pk4fp8(f[4], f[5], f[6], f[7]);
    *(int2*)(Bp1 + ((size_t)(v0 / 16 + vbl) * 32 + k0 / 32) * 512 + lane * 8) = w2;
  }
#pragma unroll
  for (int it = 0; it < 4; ++it) {
    int idx = it * 4 + g;                 // hbl = idx>>3 (0..1), vkbl = idx&7
    int hbl = idx >> 3, vkbl = idx & 7;
    bf16x8 frag;
#pragma unroll
    for (int j = 0; j < 8; ++j) frag[j] = f2bf(tile[hbl * 16 + l15][vkbl * 32 + q * 8 + j]);
    *(bf16x8*)(Bp2 + ((size_t)(k0 / 16 + hbl) * 1000 + v0 / 32 + vkbl) * 512 + lane * 8) = frag;
  }
}

// ===================== fused u + adapted (bf16 + fp8): one block per row ===========
__global__ void k_prep_ua(const float* __restrict__ hs, const float* __restrict__ fa,
                          const float* __restrict__ fb, float* __restrict__ u,
                          short* __restrict__ adp, char* __restrict__ adp8) {
  __shared__ float wred[4][16];
  __shared__ float ubc[16];
  int row = blockIdx.x, tid = threadIdx.x, lane = tid & 63, w = tid >> 6;
  const float* hrow = hs + (size_t)row * Hdim;
  float4 hv = *(const float4*)(hrow + tid * 4);
  float ur[16];
  const float* fap = fa + (size_t)tid * 4 * Rdim;
#pragma unroll
  for (int r = 0; r < 16; ++r)
    ur[r] = hv.x * fap[r] + hv.y * fap[16 + r] + hv.z * fap[32 + r] + hv.w * fap[48 + r];
#pragma unroll
  for (int r = 0; r < 16; ++r)
#pragma unroll
    for (int off = 32; off; off >>= 1) ur[r] += __shfl_xor(ur[r], off);
  if (lane == 0) {
#pragma unroll
    for (int r = 0; r < 16; ++r) wred[w][r] = ur[r];
  }
  __syncthreads();
  if (tid < 16) {
    float s = wred[0][tid] + wred[1][tid] + wred[2][tid] + wred[3][tid];
    ubc[tid] = s;
    u[row * Rdim + tid] = s;
  }
  __syncthreads();
  float a0 = hv.x, a1 = hv.y, a2 = hv.z, a3 = hv.w;
#pragma unroll
  for (int r = 0; r < 16; ++r) {
    float uv = ubc[r];
    float4 bv = *(const float4*)(fb + r * Hdim + tid * 4);
    a0 += uv * bv.x; a1 += uv * bv.y; a2 += uv * bv.z; a3 += uv * bv.w;
  }
  short4 o; o.x = f2bf(a0); o.y = f2bf(a1); o.z = f2bf(a2); o.w = f2bf(a3);
  *(short4*)(adp + (size_t)row * Hdim + tid * 4) = o;
  *(int*)(adp8 + (size_t)row * Hdim + tid * 4) = pk4fp8(a0, a1, a2, a3);
}

// ===================== fused logits(fp8) + exp + dA partials(bf16) =================
// grid 512 (= 128 rowgroups x 4 V-splits; sp = L&3 keeps each XCD on one split),
// 512 threads (8 waves), 2 blocks/CU (LDS ~67 KB, VGPR <= 128).
__launch_bounds__(512, 4)
__global__ void k_fused(const char* __restrict__ adp8, const char* __restrict__ Bp1,
                        const short* __restrict__ Bp2, short* __restrict__ dApart,
                        float* __restrict__ zpart) {
  __shared__ __align__(16) char lA[RB * LAS];     // adapted fp8, full K        ~33 KB
  __shared__ __align__(16) char lP[RB * LPS];     // P tile bf16                ~33 KB
  __shared__ float zred[RB * 8];                  //                              1 KB
  int tid = threadIdx.x, lane = tid & 63, w = tid >> 6;      // w in [0,8)
  int q = lane >> 4, l15 = lane & 15;
  int sp = blockIdx.x & 3, rg = blockIdx.x >> 2;
  int row0 = rg * RB;
  int v0beg = sp * SPW;

  // stage adapted fp8 rows once (read-only afterwards)
#pragma unroll
  for (int i = 0; i < 8; ++i) {
    int idx = tid + i * 512;
    int r = idx >> 7, kk8 = (idx & 127) * 8;
    *(int2*)(lA + r * LAS + kk8) = *(const int2*)(adp8 + (size_t)(row0 + r) * Hdim + kk8);
  }

  float zacc[8];
  f32x4 acc[2][8];
#pragma unroll
  for (int j = 0; j < 8; ++j) zacc[j] = 0.f;
#pragma unroll
  for (int rf = 0; rf < 2; ++rf)
#pragma unroll
    for (int cf = 0; cf < 8; ++cf)
#pragma unroll
      for (int i = 0; i < 4; ++i) acc[rf][cf][i] = 0.f;

  __syncthreads();

  for (int t = 0; t < 16; ++t) {
    int v0 = v0beg + t * VT;
    int rem = (t == 15) ? 320 : 512;    // 8000 = 15*512 + 320 (every split)
    // ---------- phase 1 (fp8): logits; wave w owns cols w*64..+64 ----------
    f32x4 lacc[2][4];
#pragma unroll
    for (int rf = 0; rf < 2; ++rf)
#pragma unroll
      for (int cf = 0; cf < 4; ++cf)
#pragma unroll
        for (int i = 0; i < 4; ++i) lacc[rf][cf][i] = 0.f;
#pragma unroll 8
    for (int ks = 0; ks < 32; ++ks) {
      int kk = ks * 32 + q * 8;         // byte offset (1B/elem)
      long af[2], bfr[4];
      af[0] = *(const long*)(lA + l15 * LAS + kk);
      af[1] = *(const long*)(lA + (16 + l15) * LAS + kk);
#pragma unroll
      for (int cf = 0; cf < 4; ++cf) {
        int vb = v0 / 16 + w * 4 + cf;
        if (vb > 1999) vb = 1999;       // clamp (tail; results gated by rem)
        bfr[cf] = *(const long*)(Bp1 + ((size_t)vb * 32 + ks) * 512 + lane * 8);
      }
#pragma unroll
      for (int rf = 0; rf < 2; ++rf)
#pragma unroll
        for (int cf = 0; cf < 4; ++cf)
          lacc[rf][cf] = mfma8(af[rf], bfr[cf], lacc[rf][cf]);
    }
    // ---------- phase 2: P = exp(l) (m=0) -> lP bf16; Z per-thread ----------
#pragma unroll
    for (int rf = 0; rf < 2; ++rf)
#pragma unroll
      for (int i = 0; i < 4; ++i) {
        int r = rf * 16 + q * 4 + i;
#pragma unroll
        for (int cf = 0; cf < 4; ++cf) {
          int c0 = w * 64 + cf * 16;
          float pv = (c0 < rem) ? __expf(lacc[rf][cf][i]) : 0.f;
          zacc[rf * 4 + i] += pv;
          *(short*)(lP + r * LPS + (c0 + l15) * 2) = f2bf(pv);
        }
      }
    __syncthreads();                    // lP RAW
    // ---------- phase 3 (bf16): acc += P @ lm_head^T; wave w owns h w*128..+128 ----
#pragma unroll 4
    for (int ks = 0; ks < 16; ++ks) {
      int kb2 = ks * 64 + q * 16;       // byte offset in lP row
      int vkb = v0 / 32 + ks;
      if (vkb > 999) vkb = 999;         // clamp (tail; P=0 there)
      bf16x8 pa[2], bg[8];
      pa[0] = *(const bf16x8*)(lP + l15 * LPS + kb2);
      pa[1] = *(const bf16x8*)(lP + (16 + l15) * LPS + kb2);
#pragma unroll
      for (int cf = 0; cf < 8; ++cf)
        bg[cf] = *(const bf16x8*)(Bp2 + ((size_t)(w * 8 + cf) * 1000 + vkb) * 512 + lane * 8);
#pragma unroll
      for (int rf = 0; rf < 2; ++rf)
#pragma unroll
        for (int cf = 0; cf < 8; ++cf)
          acc[rf][cf] = mfma16(pa[rf], bg[cf], acc[rf][cf]);
    }
    __syncthreads();                    // lP WAR before next tile's phase 2
  }
  // ---------- epilogue: Z reduce + dA-partial stores ----------
#pragma unroll
  for (int rf = 0; rf < 2; ++rf)
#pragma unroll
    for (int i = 0; i < 4; ++i) {
      float z = zacc[rf * 4 + i];
#pragma unroll
      for (int off = 1; off < 16; off <<= 1) z += __shfl_xor(z, off);
      if (l15 == 0) zred[(rf * 16 + q * 4 + i) * 8 + w] = z;
    }
  __syncthreads();
  if (tid < RB) {
    float z = 0.f;
#pragma unroll
    for (int g = 0; g < 8; ++g) z += zred[tid * 8 + g];
    zpart[sp * ROWS + row0 + tid] = z;
  }
#pragma unroll
  for (int rf = 0; rf < 2; ++rf)
#pragma unroll
    for (int cf = 0; cf < 8; ++cf)
#pragma unroll
      for (int i = 0; i < 4; ++i) {
        int r = rf * 16 + q * 4 + i;
        int h = w * 128 + cf * 16 + l15;
        dApart[((size_t)(row0 + r) * 4 + sp) * Hdim + h] = f2bf(acc[rf][cf][i]);
      }
}

// ========== merge 4 partials + target term (Bp2 bf16 gather) + du + loss ==========
__global__ void k_post_du(const short* __restrict__ adp, const short* __restrict__ Bp2,
                          const float* __restrict__ fb, const int* __restrict__ ids,
                          const float* __restrict__ zpart, char* __restrict__ dAx,
                          float* __restrict__ du, float* __restrict__ loss_acc) {
  __shared__ float red[256];
  __shared__ float wredu[4][16];
  int row = blockIdx.x, tid = threadIdx.x, lane = tid & 63, w = tid >> 6;
  int b = row >> 11, s = row & 2047;
  bool valid = s < 2047;
  float Z = zpart[row] + zpart[ROWS + row] + zpart[2 * ROWS + row] + zpart[3 * ROWS + row];
  float sc = 1.f / (Z * NVALID);
  int tgt = valid ? ids[b * 2048 + s + 1] : 0;
  const short* prow = (const short*)(dAx + (size_t)row * 8192);
  short4 p0 = *(const short4*)(prow + tid * 4);
  short4 p1 = *(const short4*)(prow + 1024 + tid * 4);
  short4 p2 = *(const short4*)(prow + 2048 + tid * 4);
  short4 p3 = *(const short4*)(prow + 3072 + tid * 4);
  short4 a4 = *(const short4*)(adp + (size_t)row * Hdim + tid * 4);
  int tq = (tgt >> 3) & 3, tj = tgt & 7, tvkb = tgt >> 5;
  float lcv[4], d[4];
#pragma unroll
  for (int c = 0; c < 4; ++c) {
    int h = tid * 4 + c;
    // lm_head[h][tgt] from packed bf16 Bp2 (16B-granular gather)
    short lcs = Bp2[((size_t)(h >> 4) * 1000 + tvkb) * 512 +
                    (size_t)(((h & 15) + 16 * tq) * 8 + tj)];
    lcv[c] = bf2f(lcs);
  }
  float q0[4] = {bf2f(p0.x), bf2f(p0.y), bf2f(p0.z), bf2f(p0.w)};
  float q1[4] = {bf2f(p1.x), bf2f(p1.y), bf2f(p1.z), bf2f(p1.w)};
  float q2[4] = {bf2f(p2.x), bf2f(p2.y), bf2f(p2.z), bf2f(p2.w)};
  float q3[4] = {bf2f(p3.x), bf2f(p3.y), bf2f(p3.z), bf2f(p3.w)};
  float avv[4] = {bf2f(a4.x), bf2f(a4.y), bf2f(a4.z), bf2f(a4.w)};
#pragma unroll
  for (int c = 0; c < 4; ++c)
    d[c] = valid ? ((q0[c] + q1[c] + q2[c] + q3[c]) * sc - lcv[c] * (1.f / NVALID)) : 0.f;
  __syncthreads();                          // all bf16 partial reads before f32 overwrite
  float* drow = (float*)(dAx + (size_t)row * 8192);   // stride 2048 floats
  float dot = 0.f;
#pragma unroll
  for (int c = 0; c < 4; ++c) {
    drow[tid * 4 + c] = d[c];
    dot += avv[c] * lcv[c];
  }
  // du[r] = sum_h dA[h] * fb[r][h]
  float pdu[16];
#pragma unroll
  for (int r = 0; r < 16; ++r) {
    float4 bv = *(const float4*)(fb + r * Hdim + tid * 4);
    pdu[r] = d[0] * bv.x + d[1] * bv.y + d[2] * bv.z + d[3] * bv.w;
  }
#pragma unroll
  for (int r = 0; r < 16; ++r)
#pragma unroll
    for (int off = 32; off; off >>= 1) pdu[r] += __shfl_xor(pdu[r], off);
  if (lane == 0) {
#pragma unroll
    for (int r = 0; r < 16; ++r) wredu[w][r] = pdu[r];
  }
  red[tid] = dot;
  __syncthreads();
  if (tid < 16)
    du[row * Rdim + tid] = wredu[0][tid] + wredu[1][tid] + wredu[2][tid] + wredu[3][tid];
  if (!valid) return;                       // block-uniform
  for (int o = 128; o; o >>= 1) {
    if (tid < o) red[tid] += red[tid + o];
    __syncthreads();
  }
  if (tid == 0) atomicAdd(loss_acc, (logf(Z) - red[0]) / NVALID);
}

// ga = hs^T @ du ; gb = u^T @ dA  (dA row stride 2048 floats)
__global__ void k_ga_gb(const float* __restrict__ hs, const float* __restrict__ dA,
                        const float* __restrict__ u, const float* __restrict__ du,
                        float* __restrict__ ga, float* __restrict__ gb) {
  __shared__ float lu[512 * 16], ldu[512 * 16];
  int tid = threadIdx.x;
  int h = blockIdx.x * 256 + tid;
  int r0 = blockIdx.y * 512;
#pragma unroll
  for (int i = 0; i < 32; ++i) {
    int idx = tid + i * 256;
    lu[idx] = u[(size_t)r0 * Rdim + idx];
    ldu[idx] = du[(size_t)r0 * Rdim + idx];
  }
  __syncthreads();
  float aga[16], agb[16];
#pragma unroll
  for (int r = 0; r < 16; ++r) { aga[r] = 0.f; agb[r] = 0.f; }
  for (int rl = 0; rl < 512; ++rl) {
    int row = r0 + rl;
    float hv = hs[(size_t)row * Hdim + h];
    float dv = dA[(size_t)row * 2048 + h];
#pragma unroll
    for (int r = 0; r < 16; ++r) {
      aga[r] += hv * ldu[rl * 16 + r];
      agb[r] += lu[rl * 16 + r] * dv;
    }
  }
#pragma unroll
  for (int r = 0; r < 16; ++r) {
    atomicAdd(&ga[h * Rdim + r], aga[r]);
    atomicAdd(&gb[r * Hdim + h], agb[r]);
  }
}

// grad_norm + parameter update + scalars
__global__ void k_finalize(const float* __restrict__ fa, const float* __restrict__ fb,
                           const float* __restrict__ ga, const float* __restrict__ gb,
                           const float* __restrict__ loss_acc, float* __restrict__ out) {
  __shared__ float red[512];
  int tid = threadIdx.x;
  float s = 0.f;
  for (int i = tid; i < 32768; i += 512) {
    float g = ga[i];           // ga||gb contiguous in workspace
    s += g * g;
  }
  red[tid] = s; __syncthreads();
  for (int o = 256; o; o >>= 1) {
    if (tid < o) red[tid] += red[tid + o];
    __syncthreads();
  }
  float gn = sqrtf(red[0]);
  for (int i = tid; i < 16384; i += 512) {
    out[OUT_A + i] = fa[i] - LRATE * ga[i];
    out[OUT_B + i] = fb[i] - LRATE * gb[i];
  }
  if (tid == 0) { out[OUT_LOSS] = loss_acc[0]; out[OUT_GN] = gn; }
}

// ===================== fused u2 + out: one block per row =====================
__global__ void k_tail_uo(const float* __restrict__ hs, const float* __restrict__ outAB,
                          float* __restrict__ out) {
  __shared__ float wred[4][16];
  __shared__ float ubc[16];
  int row = blockIdx.x, tid = threadIdx.x, lane = tid & 63, w = tid >> 6;
  const float* na = outAB;              // new_a [H][R]
  const float* nb = outAB + 16384;      // new_b [R][H]
  const float* hrow = hs + (size_t)row * Hdim;
  float4 hv = *(const float4*)(hrow + tid * 4);
  float ur[16];
  const float* nap = na + (size_t)tid * 4 * Rdim;
#pragma unroll
  for (int r = 0; r < 16; ++r)
    ur[r] = hv.x * nap[r] + hv.y * nap[16 + r] + hv.z * nap[32 + r] + hv.w * nap[48 + r];
#pragma unroll
  for (int r = 0; r < 16; ++r)
#pragma unroll
    for (int off = 32; off; off >>= 1) ur[r] += __shfl_xor(ur[r], off);
  if (lane == 0) {
#pragma unroll
    for (int r = 0; r < 16; ++r) wred[w][r] = ur[r];
  }
  __syncthreads();
  if (tid < 16) ubc[tid] = wred[0][tid] + wred[1][tid] + wred[2][tid] + wred[3][tid];
  __syncthreads();
  float a0 = hv.x, a1 = hv.y, a2 = hv.z, a3 = hv.w;
#pragma unroll
  for (int r = 0; r < 16; ++r) {
    float uv = ubc[r];
    float4 bv = *(const float4*)(nb + r * Hdim + tid * 4);
    a0 += uv * bv.x; a1 += uv * bv.y; a2 += uv * bv.z; a3 += uv * bv.w;
  }
  float4 o; o.x = a0; o.y = a1; o.z = a2; o.w = a3;
  *(float4*)(out + (size_t)row * Hdim + tid * 4) = o;
}

extern "C" void kernel_launch(void* const* d_in, const int* in_sizes, int n_in,
                              void* d_out, int out_size, void* d_ws, size_t ws_size,
                              hipStream_t stream) {
  (void)in_sizes; (void)n_in; (void)out_size; (void)ws_size;
  const float* hs   = (const float*)d_in[0];
  const int*   ids  = (const int*)d_in[1];
  const float* fa   = (const float*)d_in[2];
  const float* fb   = (const float*)d_in[3];
  const float* lmhf = (const float*)d_in[4];
  float* out = (float*)d_out;
  char* ws = (char*)d_ws;

  short* Bp2    = (short*)(ws + OFF_BP2);
  char*  Bp1    = ws + OFF_BP1;
  short* adp    = (short*)(ws + OFF_ADP);
  char*  adp8   = ws + OFF_ADP8;
  char*  dAx    = ws + OFF_DAX;
  float* u      = (float*)(ws + OFF_U);
  float* du     = (float*)(ws + OFF_DU);
  float* zpart  = (float*)(ws + OFF_Z);
  float* ga     = (float*)(ws + OFF_GA);
  float* gb     = (float*)(ws + OFF_GB);
  float* loss_acc = (float*)(ws + OFF_LOSS);

  hipMemsetAsync(ws + OFF_GA, 0, 65536 * 2 + 4, stream);   // ga, gb, loss

  k_pack<<<dim3(125, 32), 256, 0, stream>>>(lmhf, Bp1, Bp2);
  k_prep_ua<<<4096, 256, 0, stream>>>(hs, fa, fb, u, adp, adp8);
  k_fused<<<512, 512, 0, stream>>>(adp8, Bp1, Bp2, (short*)dAx, zpart);
  k_post_du<<<4096, 256, 0, stream>>>(adp, Bp2, fb, ids, zpart, dAx, du, loss_acc);
  k_ga_gb<<<dim3(4, 8), 256, 0, stream>>>(hs, (float*)dAx, u, du, ga, gb);
  k_finalize<<<1, 512, 0, stream>>>(fa, fb, ga, gb, loss_acc, out);
  k_tail_uo<<<4096, 256, 0, stream>>>(hs, out + OUT_A, out);
}

// Round 13
// 1016.138 us; speedup vs baseline: 1.4729x; 1.4729x over previous
//
#include <hip/hip_runtime.h>
#include <hip/hip_bf16.h>

// ---------------------------------------------------------------------------
// TTT meta-adapter fused step, round 13.
// rows = B*S = 4096, H = 1024, R = 16, V = 32000, N_valid = 4094.
// k_fused: R11 geometry VERBATIM (16 waves, grid 256, 2 V-splits, acc[2][4]
// -- the proven no-spill config) with ONLY phase-1 switched to fp8 e4m3
// (Bp1 + lA; numerics proven in R12): per-CU B traffic 65.6->49.2 MB.
// Gradient path (P, Bp2, phase 3) stays bf16. m=0 softmax.
// ---------------------------------------------------------------------------

#define ROWS 4096
#define Hdim 1024
#define Rdim 16
#define Vdim 32000
#define NVALID 4094.0f
#define LRATE 0.01f
#define RB 32          // rows per block in fused kernel
#define VT 512         // V-tile
#define LAS 1032       // lA row stride bytes (fp8, padded: conflict-free)

typedef __attribute__((ext_vector_type(8))) short bf16x8;
typedef __attribute__((ext_vector_type(4))) float f32x4;

static __device__ __forceinline__ float bf2f(short u) {
  union { float f; unsigned int i; } w; w.i = ((unsigned int)(unsigned short)u) << 16; return w.f;
}
static __device__ __forceinline__ short f2bf(float f) {
  union { float f; unsigned int i; } w; w.f = f;
  unsigned int lsb = (w.i >> 16) & 1u;
  w.i += 0x7fffu + lsb;                 // round-to-nearest-even
  return (short)(w.i >> 16);
}
static __device__ __forceinline__ f32x4 mfma16(bf16x8 a, bf16x8 b, f32x4 c) {
  return __builtin_amdgcn_mfma_f32_16x16x32_bf16(a, b, c, 0, 0, 0);
}
static __device__ __forceinline__ f32x4 mfma8(long a, long b, f32x4 c) {
  return __builtin_amdgcn_mfma_f32_16x16x32_fp8_fp8(a, b, c, 0, 0, 0);
}
static __device__ __forceinline__ int pk4fp8(float f0, float f1, float f2, float f3) {
  int v = __builtin_amdgcn_cvt_pk_fp8_f32(f0, f1, 0, false);
  v = __builtin_amdgcn_cvt_pk_fp8_f32(f2, f3, v, true);
  return v;
}

// ---------------- workspace layout (bytes) ----------------
#define OFF_BP2   ((size_t)0)                    // lm_head bf16 packed [64][1000][512]   65,536,000
#define OFF_BP1   ((size_t)65536000)             // lmhT fp8 packed [2000][32][512B]      32,768,000
#define OFF_ADP   ((size_t)98304000)             // adapted bf16 [ROWS][H]                 8,388,608
#define OFF_ADP8  ((size_t)106692608)            // adapted fp8 [ROWS][H]                  4,194,304
#define OFF_DA    ((size_t)110886912)            // dApart bf16 [ROWS][2][H]; f32 overlay 16,777,216
#define OFF_U     ((size_t)127664128)            // u f32                                    262,144
#define OFF_DU    ((size_t)127926272)            // du f32                                   262,144
#define OFF_Z     ((size_t)128188416)            // zpart f32 [2][ROWS]                       32,768
#define OFF_GA    ((size_t)128221184)            // ga f32                                    65,536
#define OFF_GB    ((size_t)128286720)            // gb f32                                    65,536
#define OFF_LOSS  ((size_t)128352256)            // loss accumulator                               4

// ---------------- output layout (floats) ----------------
#define OUT_A    ((size_t)4194304)
#define OUT_B    ((size_t)4210688)
#define OUT_LOSS ((size_t)4227072)
#define OUT_GN   ((size_t)4227073)

// ===================== pack lm_head: Bp1 fp8 (v-major), Bp2 bf16 (h-major) ==========
// Bp1[vb][kb][lane][8B]: elem (v,k)=lm_head[k][v], lane=(v&15)+16*((k>>3)&3), j=k&7
// Bp2[hb][vkb][lane][8]: elem (h,v)=lm_head[h][v], lane=(h&15)+16*((v>>3)&3), j=v&7
__global__ void k_pack(const float* __restrict__ in, char* __restrict__ Bp1,
                       short* __restrict__ Bp2) {
  __shared__ float tile[32][260];
  int v0 = blockIdx.x * 256, k0 = blockIdx.y * 32;
  int tid = threadIdx.x;
#pragma unroll
  for (int r = 0; r < 32; ++r)
    tile[r][tid] = in[(size_t)(k0 + r) * Vdim + v0 + tid];
  __syncthreads();
  int lane = tid & 63, l15 = lane & 15, q = (lane >> 4) & 3, g = tid >> 6;
#pragma unroll
  for (int it = 0; it < 4; ++it) {
    int vbl = it * 4 + g;                 // 0..15
    float f[8];
#pragma unroll
    for (int j = 0; j < 8; ++j) f[j] = tile[q * 8 + j][vbl * 16 + l15];
    int2 w2;
    w2.x = pk4fp8(f[0], f[1], f[2], f[3]);
    w2.y = pk4fp8(f[4], f[5], f[6], f[7]);
    *(int2*)(Bp1 + ((size_t)(v0 / 16 + vbl) * 32 + k0 / 32) * 512 + lane * 8) = w2;
  }
#pragma unroll
  for (int it = 0; it < 4; ++it) {
    int idx = it * 4 + g;                 // hbl = idx>>3 (0..1), vkbl = idx&7
    int hbl = idx >> 3, vkbl = idx & 7;
    bf16x8 frag;
#pragma unroll
    for (int j = 0; j < 8; ++j) frag[j] = f2bf(tile[hbl * 16 + l15][vkbl * 32 + q * 8 + j]);
    *(bf16x8*)(Bp2 + ((size_t)(k0 / 16 + hbl) * 1000 + v0 / 32 + vkbl) * 512 + lane * 8) = frag;
  }
}

// ===================== fused u + adapted (bf16 + fp8): one block per row ===========
__global__ void k_prep_ua(const float* __restrict__ hs, const float* __restrict__ fa,
                          const float* __restrict__ fb, float* __restrict__ u,
                          short* __restrict__ adp, char* __restrict__ adp8) {
  __shared__ float wred[4][16];
  __shared__ float ubc[16];
  int row = blockIdx.x, tid = threadIdx.x, lane = tid & 63, w = tid >> 6;
  const float* hrow = hs + (size_t)row * Hdim;
  float4 hv = *(const float4*)(hrow + tid * 4);
  float ur[16];
  const float* fap = fa + (size_t)tid * 4 * Rdim;
#pragma unroll
  for (int r = 0; r < 16; ++r)
    ur[r] = hv.x * fap[r] + hv.y * fap[16 + r] + hv.z * fap[32 + r] + hv.w * fap[48 + r];
#pragma unroll
  for (int r = 0; r < 16; ++r)
#pragma unroll
    for (int off = 32; off; off >>= 1) ur[r] += __shfl_xor(ur[r], off);
  if (lane == 0) {
#pragma unroll
    for (int r = 0; r < 16; ++r) wred[w][r] = ur[r];
  }
  __syncthreads();
  if (tid < 16) {
    float s = wred[0][tid] + wred[1][tid] + wred[2][tid] + wred[3][tid];
    ubc[tid] = s;
    u[row * Rdim + tid] = s;
  }
  __syncthreads();
  float a0 = hv.x, a1 = hv.y, a2 = hv.z, a3 = hv.w;
#pragma unroll
  for (int r = 0; r < 16; ++r) {
    float uv = ubc[r];
    float4 bv = *(const float4*)(fb + r * Hdim + tid * 4);
    a0 += uv * bv.x; a1 += uv * bv.y; a2 += uv * bv.z; a3 += uv * bv.w;
  }
  short4 o; o.x = f2bf(a0); o.y = f2bf(a1); o.z = f2bf(a2); o.w = f2bf(a3);
  *(short4*)(adp + (size_t)row * Hdim + tid * 4) = o;
  *(int*)(adp8 + (size_t)row * Hdim + tid * 4) = pk4fp8(a0, a1, a2, a3);
}

// ===================== fused logits(fp8) + exp + dA partials(bf16) =================
// grid 256 (XCD-swizzled -> 128 rowgroups x 2 V-splits), 1024 threads (16 waves).
__launch_bounds__(1024, 4)
__global__ void k_fused(const char* __restrict__ adp8, const char* __restrict__ Bp1,
                        const short* __restrict__ Bp2, short* __restrict__ dApart,
                        float* __restrict__ zpart) {
  __shared__ __align__(16) char lA[RB * LAS];     // adapted fp8, full K       ~33 KB
  __shared__ __align__(16) short lP[2][RB * VT];  // P tile bf16, dbuf        2x32 KB
  __shared__ float zred[RB * 16];                 //                             2 KB
  int tid = threadIdx.x, lane = tid & 63, w = tid >> 6;      // w in [0,16)
  int q = lane >> 4, l15 = lane & 15;
  // XCD swizzle: XCDs 0-3 get split 0, XCDs 4-7 get split 1
  int L = blockIdx.x;
  int sp = (L >> 2) & 1;
  int rg = (L & 3) | ((L >> 3) << 2);
  int row0 = rg * RB;
  int v0beg = sp ? 15872 : 0;
  int v0end = sp ? 32000 : 15872;
  int nt = sp ? 32 : 31;

  // stage adapted fp8 rows once (read-only afterwards)
#pragma unroll
  for (int i = 0; i < 4; ++i) {
    int idx = tid + i * 1024;
    int r = idx >> 7, kk8 = (idx & 127) * 8;
    *(int2*)(lA + r * LAS + kk8) = *(const int2*)(adp8 + (size_t)(row0 + r) * Hdim + kk8);
  }
  if (tid < RB * 16) zred[tid] = 0.f;

  f32x4 acc[2][4];
#pragma unroll
  for (int rf = 0; rf < 2; ++rf)
#pragma unroll
    for (int cf = 0; cf < 4; ++cf)
#pragma unroll
      for (int i = 0; i < 4; ++i) acc[rf][cf][i] = 0.f;

  __syncthreads();

  for (int t = 0; t < nt; ++t) {
    int v0 = v0beg + t * VT;
    int rem = v0end - v0; if (rem > VT) rem = VT;   // 512, except 256 on sp1 tail
    char* lPc = (char*)lP[t & 1];
    // ---------- phase 1 (fp8): logits; wave w owns cols w*32..+32 ----------
    f32x4 lacc[2][2];
#pragma unroll
    for (int rf = 0; rf < 2; ++rf)
#pragma unroll
      for (int cf = 0; cf < 2; ++cf)
#pragma unroll
        for (int i = 0; i < 4; ++i) lacc[rf][cf][i] = 0.f;
#pragma unroll 8
    for (int ks = 0; ks < 32; ++ks) {
      int kk = ks * 32 + q * 8;         // byte offset (1B/elem)
      long af[2], bfr[2];
      af[0] = *(const long*)(lA + l15 * LAS + kk);
      af[1] = *(const long*)(lA + (16 + l15) * LAS + kk);
#pragma unroll
      for (int cf = 0; cf < 2; ++cf) {
        int vb = v0 / 16 + w * 2 + cf;
        if (vb > 1999) vb = 1999;       // clamp (sp1 tail; results gated by rem)
        bfr[cf] = *(const long*)(Bp1 + ((size_t)vb * 32 + ks) * 512 + lane * 8);
      }
#pragma unroll
      for (int rf = 0; rf < 2; ++rf)
#pragma unroll
        for (int cf = 0; cf < 2; ++cf)
          lacc[rf][cf] = mfma8(af[rf], bfr[cf], lacc[rf][cf]);
    }
    // ---------- phase 2: P = exp(l) (m=0) -> lP[t&1]; Z into zred ----------
#pragma unroll
    for (int rf = 0; rf < 2; ++rf)
#pragma unroll
      for (int i = 0; i < 4; ++i) {
        int r = rf * 16 + q * 4 + i;
        float z = 0.f;
#pragma unroll
        for (int cf = 0; cf < 2; ++cf) {
          int c0 = w * 32 + cf * 16;
          float pv = (c0 < rem) ? __expf(lacc[rf][cf][i]) : 0.f;
          z += pv;
          int c = c0 + l15;
          *(short*)(lPc + r * 1024 + ((c * 2) ^ ((r & 7) << 4))) = f2bf(pv);
        }
#pragma unroll
        for (int off = 1; off < 16; off <<= 1) z += __shfl_xor(z, off);
        if (l15 == 0) zred[r * 16 + w] += z;
      }
    __syncthreads();                    // ONLY barrier: lP[t&1] RAW
    // ---------- phase 3 (bf16): acc += P @ lm_head^T; wave w owns h w*64..+64 ------
#pragma unroll 4
    for (int ks = 0; ks < 16; ++ks) {
      int kb = ks * 32 + q * 8;
      int vkb = v0 / 32 + ks;
      if (vkb > 999) vkb = 999;         // clamp (tail; P=0 there)
      bf16x8 pa[2], bg[4];
#pragma unroll
      for (int rf = 0; rf < 2; ++rf) {
        int r = rf * 16 + l15;
        pa[rf] = *(const bf16x8*)(lPc + r * 1024 + ((kb * 2) ^ ((r & 7) << 4)));
      }
#pragma unroll
      for (int cf = 0; cf < 4; ++cf)
        bg[cf] = *(const bf16x8*)(Bp2 + ((size_t)(w * 4 + cf) * 1000 + vkb) * 512 + lane * 8);
#pragma unroll
      for (int rf = 0; rf < 2; ++rf)
#pragma unroll
        for (int cf = 0; cf < 4; ++cf)
          acc[rf][cf] = mfma16(pa[rf], bg[cf], acc[rf][cf]);
    }
    // no trailing barrier: next tile writes the OTHER lP buffer (max drift 1 tile)
  }
  // ---------- epilogue: Z totals + dA-partial stores ----------
  __syncthreads();
  if (tid < RB) {
    float z = 0.f;
#pragma unroll
    for (int g = 0; g < 16; ++g) z += zred[tid * 16 + g];
    zpart[sp * ROWS + row0 + tid] = z;
  }
#pragma unroll
  for (int rf = 0; rf < 2; ++rf)
#pragma unroll
    for (int cf = 0; cf < 4; ++cf)
#pragma unroll
      for (int i = 0; i < 4; ++i) {
        int r = rf * 16 + q * 4 + i;
        int h = w * 64 + cf * 16 + l15;
        dApart[((size_t)(row0 + r) * 2 + sp) * Hdim + h] = f2bf(acc[rf][cf][i]);
      }
}

// ========== merge partials + target term (Bp2 bf16 gather) + du + loss ==========
__global__ void k_post_du(const short* __restrict__ adp, const short* __restrict__ Bp2,
                          const float* __restrict__ fb, const int* __restrict__ ids,
                          const float* __restrict__ zpart, char* __restrict__ dAx,
                          float* __restrict__ du, float* __restrict__ loss_acc) {
  __shared__ float red[256];
  __shared__ float wredu[4][16];
  int row = blockIdx.x, tid = threadIdx.x, lane = tid & 63, w = tid >> 6;
  int b = row >> 11, s = row & 2047;
  bool valid = s < 2047;
  float Z = zpart[row] + zpart[ROWS + row];
  float sc = 1.f / (Z * NVALID);
  int tgt = valid ? ids[b * 2048 + s + 1] : 0;
  const short* prow = (const short*)(dAx + (size_t)row * 4096);
  short4 p0 = *(const short4*)(prow + tid * 4);
  short4 p1 = *(const short4*)(prow + 1024 + tid * 4);
  short4 a4 = *(const short4*)(adp + (size_t)row * Hdim + tid * 4);
  int tq = (tgt >> 3) & 3, tj = tgt & 7, tvkb = tgt >> 5;
  float lcv[4], d[4];
#pragma unroll
  for (int c = 0; c < 4; ++c) {
    int h = tid * 4 + c;
    // lm_head[h][tgt] from packed bf16 Bp2 (16B-granular gather)
    short lcs = Bp2[((size_t)(h >> 4) * 1000 + tvkb) * 512 +
                    (size_t)(((h & 15) + 16 * tq) * 8 + tj)];
    lcv[c] = bf2f(lcs);
  }
  float q0[4] = {bf2f(p0.x), bf2f(p0.y), bf2f(p0.z), bf2f(p0.w)};
  float q1[4] = {bf2f(p1.x), bf2f(p1.y), bf2f(p1.z), bf2f(p1.w)};
  float avv[4] = {bf2f(a4.x), bf2f(a4.y), bf2f(a4.z), bf2f(a4.w)};
#pragma unroll
  for (int c = 0; c < 4; ++c)
    d[c] = valid ? ((q0[c] + q1[c]) * sc - lcv[c] * (1.f / NVALID)) : 0.f;
  __syncthreads();                          // all bf16 partial reads before f32 overwrite
  float* drow = (float*)(dAx + (size_t)row * 4096);
  float dot = 0.f;
#pragma unroll
  for (int c = 0; c < 4; ++c) {
    drow[tid * 4 + c] = d[c];
    dot += avv[c] * lcv[c];
  }
  // du[r] = sum_h dA[h] * fb[r][h]
  float pdu[16];
#pragma unroll
  for (int r = 0; r < 16; ++r) {
    float4 bv = *(const float4*)(fb + r * Hdim + tid * 4);
    pdu[r] = d[0] * bv.x + d[1] * bv.y + d[2] * bv.z + d[3] * bv.w;
  }
#pragma unroll
  for (int r = 0; r < 16; ++r)
#pragma unroll
    for (int off = 32; off; off >>= 1) pdu[r] += __shfl_xor(pdu[r], off);
  if (lane == 0) {
#pragma unroll
    for (int r = 0; r < 16; ++r) wredu[w][r] = pdu[r];
  }
  red[tid] = dot;
  __syncthreads();
  if (tid < 16)
    du[row * Rdim + tid] = wredu[0][tid] + wredu[1][tid] + wredu[2][tid] + wredu[3][tid];
  if (!valid) return;                       // block-uniform
  for (int o = 128; o; o >>= 1) {
    if (tid < o) red[tid] += red[tid + o];
    __syncthreads();
  }
  if (tid == 0) atomicAdd(loss_acc, (logf(Z) - red[0]) / NVALID);
}

// ga = hs^T @ du ; gb = u^T @ dA  (atomic partials over row chunks)
__global__ void k_ga_gb(const float* __restrict__ hs, const float* __restrict__ dA,
                        const float* __restrict__ u, const float* __restrict__ du,
                        float* __restrict__ ga, float* __restrict__ gb) {
  __shared__ float lu[512 * 16], ldu[512 * 16];
  int tid = threadIdx.x;
  int h = blockIdx.x * 256 + tid;
  int r0 = blockIdx.y * 512;
#pragma unroll
  for (int i = 0; i < 32; ++i) {
    int idx = tid + i * 256;
    lu[idx] = u[(size_t)r0 * Rdim + idx];
    ldu[idx] = du[(size_t)r0 * Rdim + idx];
  }
  __syncthreads();
  float aga[16], agb[16];
#pragma unroll
  for (int r = 0; r < 16; ++r) { aga[r] = 0.f; agb[r] = 0.f; }
  for (int rl = 0; rl < 512; ++rl) {
    int row = r0 + rl;
    float hv = hs[(size_t)row * Hdim + h];
    float dv = dA[(size_t)row * Hdim + h];
#pragma unroll
    for (int r = 0; r < 16; ++r) {
      aga[r] += hv * ldu[rl * 16 + r];
      agb[r] += lu[rl * 16 + r] * dv;
    }
  }
#pragma unroll
  for (int r = 0; r < 16; ++r) {
    atomicAdd(&ga[h * Rdim + r], aga[r]);
    atomicAdd(&gb[r * Hdim + h], agb[r]);
  }
}

// grad_norm + parameter update + scalars
__global__ void k_finalize(const float* __restrict__ fa, const float* __restrict__ fb,
                           const float* __restrict__ ga, const float* __restrict__ gb,
                           const float* __restrict__ loss_acc, float* __restrict__ out) {
  __shared__ float red[512];
  int tid = threadIdx.x;
  float s = 0.f;
  for (int i = tid; i < 32768; i += 512) {
    float g = ga[i];           // ga||gb contiguous in workspace
    s += g * g;
  }
  red[tid] = s; __syncthreads();
  for (int o = 256; o; o >>= 1) {
    if (tid < o) red[tid] += red[tid + o];
    __syncthreads();
  }
  float gn = sqrtf(red[0]);
  for (int i = tid; i < 16384; i += 512) {
    out[OUT_A + i] = fa[i] - LRATE * ga[i];
    out[OUT_B + i] = fb[i] - LRATE * gb[i];
  }
  if (tid == 0) { out[OUT_LOSS] = loss_acc[0]; out[OUT_GN] = gn; }
}

// ===================== fused u2 + out: one block per row =====================
__global__ void k_tail_uo(const float* __restrict__ hs, const float* __restrict__ outAB,
                          float* __restrict__ out) {
  __shared__ float wred[4][16];
  __shared__ float ubc[16];
  int row = blockIdx.x, tid = threadIdx.x, lane = tid & 63, w = tid >> 6;
  const float* na = outAB;              // new_a [H][R]
  const float* nb = outAB + 16384;      // new_b [R][H]
  const float* hrow = hs + (size_t)row * Hdim;
  float4 hv = *(const float4*)(hrow + tid * 4);
  float ur[16];
  const float* nap = na + (size_t)tid * 4 * Rdim;
#pragma unroll
  for (int r = 0; r < 16; ++r)
    ur[r] = hv.x * nap[r] + hv.y * nap[16 + r] + hv.z * nap[32 + r] + hv.w * nap[48 + r];
#pragma unroll
  for (int r = 0; r < 16; ++r)
#pragma unroll
    for (int off = 32; off; off >>= 1) ur[r] += __shfl_xor(ur[r], off);
  if (lane == 0) {
#pragma unroll
    for (int r = 0; r < 16; ++r) wred[w][r] = ur[r];
  }
  __syncthreads();
  if (tid < 16) ubc[tid] = wred[0][tid] + wred[1][tid] + wred[2][tid] + wred[3][tid];
  __syncthreads();
  float a0 = hv.x, a1 = hv.y, a2 = hv.z, a3 = hv.w;
#pragma unroll
  for (int r = 0; r < 16; ++r) {
    float uv = ubc[r];
    float4 bv = *(const float4*)(nb + r * Hdim + tid * 4);
    a0 += uv * bv.x; a1 += uv * bv.y; a2 += uv * bv.z; a3 += uv * bv.w;
  }
  float4 o; o.x = a0; o.y = a1; o.z = a2; o.w = a3;
  *(float4*)(out + (size_t)row * Hdim + tid * 4) = o;
}

extern "C" void kernel_launch(void* const* d_in, const int* in_sizes, int n_in,
                              void* d_out, int out_size, void* d_ws, size_t ws_size,
                              hipStream_t stream) {
  (void)in_sizes; (void)n_in; (void)out_size; (void)ws_size;
  const float* hs   = (const float*)d_in[0];
  const int*   ids  = (const int*)d_in[1];
  const float* fa   = (const float*)d_in[2];
  const float* fb   = (const float*)d_in[3];
  const float* lmhf = (const float*)d_in[4];
  float* out = (float*)d_out;
  char* ws = (char*)d_ws;

  short* Bp2    = (short*)(ws + OFF_BP2);
  char*  Bp1    = ws + OFF_BP1;
  short* adp    = (short*)(ws + OFF_ADP);
  char*  adp8   = ws + OFF_ADP8;
  char*  dAx    = ws + OFF_DA;
  float* u      = (float*)(ws + OFF_U);
  float* du     = (float*)(ws + OFF_DU);
  float* zpart  = (float*)(ws + OFF_Z);
  float* ga     = (float*)(ws + OFF_GA);
  float* gb     = (float*)(ws + OFF_GB);
  float* loss_acc = (float*)(ws + OFF_LOSS);

  hipMemsetAsync(ws + OFF_GA, 0, 65536 * 2 + 4, stream);   // ga, gb, loss

  k_pack<<<dim3(125, 32), 256, 0, stream>>>(lmhf, Bp1, Bp2);
  k_prep_ua<<<4096, 256, 0, stream>>>(hs, fa, fb, u, adp, adp8);
  k_fused<<<256, 1024, 0, stream>>>(adp8, Bp1, Bp2, (short*)dAx, zpart);
  k_post_du<<<4096, 256, 0, stream>>>(adp, Bp2, fb, ids, zpart, dAx, du, loss_acc);
  k_ga_gb<<<dim3(4, 8), 256, 0, stream>>>(hs, (float*)dAx, u, du, ga, gb);
  k_finalize<<<1, 512, 0, stream>>>(fa, fb, ga, gb, loss_acc, out);
  k_tail_uo<<<4096, 256, 0, stream>>>(hs, out + OUT_A, out);
}